// Round 1
// baseline (95.098 us; speedup 1.0000x reference)
//
#include <hip/hip_runtime.h>
#include <math.h>

// Problem constants (from reference): D = 768 -> 192 float4 chunks -> 3 per lane.
#define DIM 768
#define CHUNKS 3          // float4 chunks per lane: 192 / 64
#define WAVES_PER_BLOCK 4 // 256 threads

// One wave (64 lanes) per word. Single fused pass:
//   for each subword s in [start, end):
//     row = emb[s]            (held in registers, 12 floats/lane)
//     score = row . attn_w + b  (wave shuffle-reduction)
//     online-softmax update of (m, l, acc)
//   out[word] = acc / l
// Each embedding row is read exactly once from HBM (spans partition subwords),
// so total traffic ~= 50.3 MB read + 25.2 MB write -> memory-bound floor ~12 us.
__global__ __launch_bounds__(256) void word_pool_kernel(
    const float* __restrict__ emb,     // [n_subwords, DIM]
    const int*   __restrict__ offsets, // [n_words, 2]
    const float* __restrict__ attn_w,  // [DIM]
    const float* __restrict__ attn_b,  // [1]
    float*       __restrict__ out,     // [n_words, DIM]
    int n_words)
{
    const int wave = (int)((blockIdx.x * blockDim.x + threadIdx.x) >> 6);
    const int lane = (int)(threadIdx.x & 63);
    if (wave >= n_words) return;

    const float bias = attn_b[0];

    // Per-lane fragment of attn_w: float4 chunks {lane, lane+64, lane+128}.
    // Broadcast across all waves -> lives in L1/L2 after first touch.
    float4 wv[CHUNKS];
    const float4* wq = (const float4*)attn_w;
#pragma unroll
    for (int j = 0; j < CHUNKS; ++j)
        wv[j] = wq[lane + 64 * j];

    const int s0 = offsets[2 * wave + 0];
    const int s1 = offsets[2 * wave + 1];

    float  m = -INFINITY;
    float  denom = 0.0f;
    float4 acc[CHUNKS];
#pragma unroll
    for (int j = 0; j < CHUNKS; ++j)
        acc[j] = make_float4(0.0f, 0.0f, 0.0f, 0.0f);

    for (int s = s0; s < s1; ++s) {
        const float4* row = (const float4*)(emb + (size_t)s * DIM);
        float4 rv[CHUNKS];
        float  partial = 0.0f;
#pragma unroll
        for (int j = 0; j < CHUNKS; ++j) {
            rv[j] = row[lane + 64 * j];
            partial += rv[j].x * wv[j].x + rv[j].y * wv[j].y
                     + rv[j].z * wv[j].z + rv[j].w * wv[j].w;
        }
        // Wave-wide sum (64 lanes, 6 butterfly steps).
#pragma unroll
        for (int off = 32; off > 0; off >>= 1)
            partial += __shfl_xor(partial, off, 64);
        const float score = partial + bias;

        // Online softmax update. First iter: m=-inf -> alpha=exp(-inf)=0.
        const float m_new = fmaxf(m, score);
        const float alpha = expf(m - m_new);
        const float p     = expf(score - m_new);
#pragma unroll
        for (int j = 0; j < CHUNKS; ++j) {
            acc[j].x = acc[j].x * alpha + rv[j].x * p;
            acc[j].y = acc[j].y * alpha + rv[j].y * p;
            acc[j].z = acc[j].z * alpha + rv[j].z * p;
            acc[j].w = acc[j].w * alpha + rv[j].w * p;
        }
        denom = denom * alpha + p;
        m = m_new;
    }

    const float inv = 1.0f / denom;
    float4* oq = (float4*)(out + (size_t)wave * DIM);
#pragma unroll
    for (int j = 0; j < CHUNKS; ++j) {
        float4 v;
        v.x = acc[j].x * inv;
        v.y = acc[j].y * inv;
        v.z = acc[j].z * inv;
        v.w = acc[j].w * inv;
        oq[lane + 64 * j] = v;
    }
}

extern "C" void kernel_launch(void* const* d_in, const int* in_sizes, int n_in,
                              void* d_out, int out_size, void* d_ws, size_t ws_size,
                              hipStream_t stream) {
    const float* emb     = (const float*)d_in[0];
    const int*   offsets = (const int*)d_in[1];
    const float* attn_w  = (const float*)d_in[2];
    const float* attn_b  = (const float*)d_in[3];
    float*       out     = (float*)d_out;

    const int n_words = in_sizes[1] / 2;  // [n_words, 2]
    const int blocks  = (n_words + WAVES_PER_BLOCK - 1) / WAVES_PER_BLOCK;

    word_pool_kernel<<<blocks, 256, 0, stream>>>(emb, offsets, attn_w, attn_b,
                                                 out, n_words);
}

// Round 3
// 94.194 us; speedup vs baseline: 1.0096x; 1.0096x over previous
//
#include <hip/hip_runtime.h>
#include <math.h>

// Problem constants (from reference): D = 768 -> 192 float4 chunks -> 3 per lane.
#define DIM 768
#define CHUNKS 3          // float4 chunks per lane: 192 / 64
#define WAVES_PER_BLOCK 4 // 256 threads

// Native clang vector type: __builtin_nontemporal_store requires a pointer to
// scalar/native-vector, not HIP's HIP_vector_type<float,4> class.
typedef float v4f __attribute__((ext_vector_type(4)));

// One wave (64 lanes) per word.
// Fast path (span length == 2, which is what setup_inputs generates):
//   issue ALL 6 row loads up-front (single memory round trip), two interleaved
//   shuffle-reduction chains for the two dot products, exact 2-way softmax via
//   a numerically-stable sigmoid of the score difference (bias cancels), then
//   out = p0*r0 + p1*r1 with nontemporal stores (write-once data).
// Generic path (any span length): single-pass online softmax.
// Each embedding row is read exactly once from HBM (spans partition subwords):
// ~50.3 MB read + 25.2 MB write -> memory-bound floor ~12 us.
__global__ __launch_bounds__(256) void word_pool_kernel(
    const float* __restrict__ emb,     // [n_subwords, DIM]
    const int*   __restrict__ offsets, // [n_words, 2]
    const float* __restrict__ attn_w,  // [DIM]
    const float* __restrict__ attn_b,  // [1]
    float*       __restrict__ out,     // [n_words, DIM]
    int n_words)
{
    int wave = (int)((blockIdx.x * blockDim.x + threadIdx.x) >> 6);
    const int lane = (int)(threadIdx.x & 63);
    if (wave >= n_words) return;
    // wave is uniform across the 64 lanes; make that explicit so the compiler
    // emits scalar loads for offsets and a scalar output base address.
    wave = __builtin_amdgcn_readfirstlane(wave);

    const int s0 = offsets[2 * wave + 0];
    const int s1 = offsets[2 * wave + 1];

    // Per-lane fragment of attn_w: v4f chunks {lane, lane+64, lane+128}.
    // Broadcast across all waves -> L2-resident after first touch.
    const v4f* wq = (const v4f*)attn_w;
    v4f wv[CHUNKS];
#pragma unroll
    for (int j = 0; j < CHUNKS; ++j)
        wv[j] = wq[lane + 64 * j];

    v4f* oq = (v4f*)(out + (size_t)wave * DIM);

    if (s1 - s0 == 2) {
        // ---- fast path: exactly two subwords ----
        const v4f* r0p = (const v4f*)(emb + (size_t)s0 * DIM);
        const v4f* r1p = r0p + (DIM / 4);
        v4f r0[CHUNKS], r1[CHUNKS];
        // Issue all 6 loads before any use -> one memory round trip.
#pragma unroll
        for (int j = 0; j < CHUNKS; ++j) r0[j] = r0p[lane + 64 * j];
#pragma unroll
        for (int j = 0; j < CHUNKS; ++j) r1[j] = r1p[lane + 64 * j];

        float d0 = 0.0f, d1 = 0.0f;
#pragma unroll
        for (int j = 0; j < CHUNKS; ++j) {
            d0 += r0[j].x * wv[j].x + r0[j].y * wv[j].y
                + r0[j].z * wv[j].z + r0[j].w * wv[j].w;
            d1 += r1[j].x * wv[j].x + r1[j].y * wv[j].y
                + r1[j].z * wv[j].z + r1[j].w * wv[j].w;
        }
        // Two independent butterfly chains, interleaved for ILP.
#pragma unroll
        for (int off = 32; off > 0; off >>= 1) {
            d0 += __shfl_xor(d0, off, 64);
            d1 += __shfl_xor(d1, off, 64);
        }
        // softmax([d0,d1]) -- bias cancels. Stable sigmoid of diff.
        const float diff = d1 - d0;
        const float t    = expf(-fabsf(diff));
        const float inv  = 1.0f / (1.0f + t);
        const float p1   = (diff >= 0.0f) ? inv : t * inv;
        const float p0   = 1.0f - p1;
#pragma unroll
        for (int j = 0; j < CHUNKS; ++j) {
            v4f v;
            v.x = p0 * r0[j].x + p1 * r1[j].x;
            v.y = p0 * r0[j].y + p1 * r1[j].y;
            v.z = p0 * r0[j].z + p1 * r1[j].z;
            v.w = p0 * r0[j].w + p1 * r1[j].w;
            __builtin_nontemporal_store(v, &oq[lane + 64 * j]);
        }
        return;
    }

    // ---- generic path: online softmax over an arbitrary span ----
    const float bias = attn_b[0];
    float m = -INFINITY;
    float denom = 0.0f;
    v4f acc[CHUNKS];
#pragma unroll
    for (int j = 0; j < CHUNKS; ++j)
        acc[j] = (v4f){0.0f, 0.0f, 0.0f, 0.0f};

    for (int s = s0; s < s1; ++s) {
        const v4f* row = (const v4f*)(emb + (size_t)s * DIM);
        v4f rv[CHUNKS];
        float partial = 0.0f;
#pragma unroll
        for (int j = 0; j < CHUNKS; ++j) {
            rv[j] = row[lane + 64 * j];
            partial += rv[j].x * wv[j].x + rv[j].y * wv[j].y
                     + rv[j].z * wv[j].z + rv[j].w * wv[j].w;
        }
#pragma unroll
        for (int off = 32; off > 0; off >>= 1)
            partial += __shfl_xor(partial, off, 64);
        const float score = partial + bias;

        const float m_new = fmaxf(m, score);
        const float alpha = expf(m - m_new);
        const float p     = expf(score - m_new);
#pragma unroll
        for (int j = 0; j < CHUNKS; ++j) {
            acc[j] = acc[j] * alpha + rv[j] * p;
        }
        denom = denom * alpha + p;
        m = m_new;
    }

    const float inv = 1.0f / denom;
#pragma unroll
    for (int j = 0; j < CHUNKS; ++j) {
        v4f v = acc[j] * inv;
        __builtin_nontemporal_store(v, &oq[lane + 64 * j]);
    }
}

extern "C" void kernel_launch(void* const* d_in, const int* in_sizes, int n_in,
                              void* d_out, int out_size, void* d_ws, size_t ws_size,
                              hipStream_t stream) {
    const float* emb     = (const float*)d_in[0];
    const int*   offsets = (const int*)d_in[1];
    const float* attn_w  = (const float*)d_in[2];
    const float* attn_b  = (const float*)d_in[3];
    float*       out     = (float*)d_out;

    const int n_words = in_sizes[1] / 2;  // [n_words, 2]
    const int blocks  = (n_words + WAVES_PER_BLOCK - 1) / WAVES_PER_BLOCK;

    word_pool_kernel<<<blocks, 256, 0, stream>>>(emb, offsets, attn_w, attn_b,
                                                 out, n_words);
}